// Round 9
// baseline (1612.871 us; speedup 1.0000x reference)
//
#include <hip/hip_runtime.h>
#include <cstdint>
#include <cstddef>

#define IMPOSSIBLE -10000.0f
#define INV_LN2 1.44269504088896340736f
#define LN2 0.69314718055994530942f

constexpr int B = 64;
constexpr int T = 2048;
constexpr int N = 128;

typedef _Float16 h2 __attribute__((ext_vector_type(2)));
typedef _Float16 h8 __attribute__((ext_vector_type(8)));

// ONE WAVE per chain; block = (batch b), 2 independent waves (w=0 sup, w=1 full).
// Lane l owns states s0=2l, s1=2l+1. E columns as f16 pairs in VGPRs (128).
// Exp-domain (r8 scheme, validated): p'_j = (sum_i p_i E_ij)*exp(em_j)/psum,
// psum = sum_i p_i of the array just read (self-referential, f16-safe bound
// p' <= maxE*exp(em) ~ 250). Mtot accumulates log2(psum).
// NO barriers, NO cross-lane ops in the loop: same-wave DS ops are in-order,
// so ds_write(own pair) -> next-step broadcast ds_read_b128 is RAW-safe.
// Matvec: 16 uniform-address (broadcast) ds_read_b128 + 192 v_dot2_f32_f16
// (4-acc chains per output: colA, colB, psum). Emissions prefetch depth 3,
// exp(em) computed off the dependent chain. Bool inputs are int32 per ABI.
// Pure function of d_in: plain stores to z_ws, no atomics, no memset.
__global__ __launch_bounds__(128, 1) void crf_chain_kernel(
    const float* __restrict__ emissions,    // [B,T,N]
    const int* __restrict__ mask,           // [B,T]
    const int* __restrict__ target,         // [B,T,N]
    const float* __restrict__ transitions,  // [N,N]
    const float* __restrict__ start_tr,     // [N]
    const float* __restrict__ end_tr,       // [N]
    const int* __restrict__ forb,           // [N,N]
    const int* __restrict__ start_forb,     // [N]
    const int* __restrict__ end_forb,       // [N]
    float* __restrict__ z_ws)               // [128]
{
    const int b = (int)blockIdx.x;          // 0..63
    const int tid = (int)threadIdx.x;
    const int w = tid >> 6;                 // wave = channel (0 sup, 1 full)
    const int lane = tid & 63;
    const int s0 = lane << 1, s1 = s0 + 1;
    const bool sup = (w == 0);

    __shared__ __align__(16) _Float16 p_lds[2][128];  // one buffer per wave

    // ---- sequence length (per-wave, independent) ----
    int lsum = 0;
    for (int k = lane; k < T; k += 64) lsum += (mask[b * T + k] != 0);
    #pragma unroll
    for (int d = 1; d < 64; d <<= 1) lsum += __shfl_xor(lsum, d);
    const int tlast = lsum - 1;

    // ---- E pairs: eA[m] = (E[2m][s0], E[2m+1][s0]), eB[m] same for s1 ----
    h2 eA[64], eB[64];
    #pragma unroll
    for (int m = 0; m < 64; ++m) {
        const float2 r0 = *reinterpret_cast<const float2*>(&transitions[(2 * m) * N + s0]);
        const float2 r1 = *reinterpret_cast<const float2*>(&transitions[(2 * m + 1) * N + s0]);
        const int2 f0 = *reinterpret_cast<const int2*>(&forb[(2 * m) * N + s0]);
        const int2 f1 = *reinterpret_cast<const int2*>(&forb[(2 * m + 1) * N + s0]);
        eA[m] = h2{(_Float16)(f0.x ? 0.0f : __expf(r0.x)),
                   (_Float16)(f1.x ? 0.0f : __expf(r1.x))};
        eB[m] = h2{(_Float16)(f0.y ? 0.0f : __expf(r0.y)),
                   (_Float16)(f1.y ? 0.0f : __expf(r1.y))};
    }

    const float* embase = emissions + (size_t)b * T * N;
    const int* tgbase = target + (size_t)b * T * N;

    // ---- t = 0 (log2 domain once; normalize so max = 1) ----
    const float2 st2 = *reinterpret_cast<const float2*>(&start_tr[s0]);
    const int2 sf2 = *reinterpret_cast<const int2*>(&start_forb[s0]);
    const float2 em02 = *reinterpret_cast<const float2*>(&embase[s0]);
    int2 tg02 = make_int2(1, 1);
    if (sup) tg02 = *reinterpret_cast<const int2*>(&tgbase[s0]);
    const float v0 = ((tg02.x ? em02.x : IMPOSSIBLE) + (sf2.x ? IMPOSSIBLE : st2.x)) * INV_LN2;
    const float v1 = ((tg02.y ? em02.y : IMPOSSIBLE) + (sf2.y ? IMPOSSIBLE : st2.y)) * INV_LN2;

    float mx = fmaxf(v0, v1);
    #pragma unroll
    for (int d = 1; d < 64; d <<= 1) mx = fmaxf(mx, __shfl_xor(mx, d));
    float Mtot = rintf(mx);
    const float p0 = exp2f(v0 - Mtot);
    const float p1 = exp2f(v1 - Mtot);
    float sv0 = p0, sv1 = p1, svM = Mtot;   // covers tlast == 0
    *reinterpret_cast<h2*>(&p_lds[w][s0]) = h2{(_Float16)p0, (_Float16)p1};

    // ---- emission prefetch depth 3; fx = exp(em(t)) computed off-path ----
    const float* emP = embase + s0;
    const int* tgP = tgbase + s0;
    float2 r1v = *reinterpret_cast<const float2*>(&emP[(size_t)1 * N]);
    int2 g1v = make_int2(1, 1);
    float2 rBv = *reinterpret_cast<const float2*>(&emP[(size_t)2 * N]);
    int2 gBv = make_int2(1, 1);
    float2 rCv = *reinterpret_cast<const float2*>(&emP[(size_t)3 * N]);
    int2 gCv = make_int2(1, 1);
    if (sup) {
        g1v = *reinterpret_cast<const int2*>(&tgP[(size_t)1 * N]);
        gBv = *reinterpret_cast<const int2*>(&tgP[(size_t)2 * N]);
        gCv = *reinterpret_cast<const int2*>(&tgP[(size_t)3 * N]);
    }
    float fx0 = g1v.x ? __expf(r1v.x) : 0.0f;
    float fx1 = g1v.y ? __expf(r1v.y) : 0.0f;

    const h8* pp = reinterpret_cast<const h8*>(p_lds[w]);
    const h2 one2 = h2{(_Float16)1.0f, (_Float16)1.0f};

    #pragma unroll 1
    for (int t = 1; t < T; ++t) {
        // broadcast read of full p (in-order DS pipe: sees last iter's write)
        float a0 = 0.f, a1 = 0.f, a2 = 0.f, a3 = 0.f;   // column s0
        float b0 = 0.f, b1 = 0.f, b2 = 0.f, b3 = 0.f;   // column s1
        float q0 = 0.f, q1 = 0.f, q2 = 0.f, q3 = 0.f;   // psum
        #pragma unroll
        for (int cch = 0; cch < 16; ++cch) {
            const h8 pv = pp[cch];
            const h2 u0 = __builtin_shufflevector(pv, pv, 0, 1);
            const h2 u1 = __builtin_shufflevector(pv, pv, 2, 3);
            const h2 u2 = __builtin_shufflevector(pv, pv, 4, 5);
            const h2 u3 = __builtin_shufflevector(pv, pv, 6, 7);
            const int m = cch << 2;
            a0 = __builtin_amdgcn_fdot2(u0, eA[m + 0], a0, false);
            a1 = __builtin_amdgcn_fdot2(u1, eA[m + 1], a1, false);
            a2 = __builtin_amdgcn_fdot2(u2, eA[m + 2], a2, false);
            a3 = __builtin_amdgcn_fdot2(u3, eA[m + 3], a3, false);
            b0 = __builtin_amdgcn_fdot2(u0, eB[m + 0], b0, false);
            b1 = __builtin_amdgcn_fdot2(u1, eB[m + 1], b1, false);
            b2 = __builtin_amdgcn_fdot2(u2, eB[m + 2], b2, false);
            b3 = __builtin_amdgcn_fdot2(u3, eB[m + 3], b3, false);
            q0 = __builtin_amdgcn_fdot2(u0, one2, q0, false);
            q1 = __builtin_amdgcn_fdot2(u1, one2, q1, false);
            q2 = __builtin_amdgcn_fdot2(u2, one2, q2, false);
            q3 = __builtin_amdgcn_fdot2(u3, one2, q3, false);
        }
        const float sA = (a0 + a1) + (a2 + a3);
        const float sB = (b0 + b1) + (b2 + b3);
        const float psum = fmaxf((q0 + q1) + (q2 + q3), 1e-30f);

        // self-referential rescale (off dependent path relative to matvec)
        const float sc = __builtin_amdgcn_rcpf(psum);
        Mtot += __log2f(psum);

        const float na0 = sA * (fx0 * sc);
        const float na1 = sB * (fx1 * sc);
        if (t == tlast) { sv0 = na0; sv1 = na1; svM = Mtot; }

        *reinterpret_cast<h2*>(&p_lds[w][s0]) = h2{(_Float16)na0, (_Float16)na1};

        // prefetch raw(t+3); produce fx for t+1 from (rB,gB)
        float2 rNv = make_float2(0.0f, 0.0f);
        int2 gNv = make_int2(1, 1);
        if (t + 3 < T) {
            rNv = *reinterpret_cast<const float2*>(&emP[(size_t)(t + 3) * N]);
            if (sup) gNv = *reinterpret_cast<const int2*>(&tgP[(size_t)(t + 3) * N]);
        }
        fx0 = gBv.x ? __expf(rBv.x) : 0.0f;
        fx1 = gBv.y ? __expf(rBv.y) : 0.0f;
        rBv = rCv; gBv = gCv;
        rCv = rNv; gCv = gNv;
    }

    // ---- z = LN2*svM + log( sum_j sv_j * exp(en_j) ) ----
    const float2 en2 = *reinterpret_cast<const float2*>(&end_tr[s0]);
    const int2 ef2 = *reinterpret_cast<const int2*>(&end_forb[s0]);
    float term = sv0 * (ef2.x ? 0.0f : __expf(en2.x))
               + sv1 * (ef2.y ? 0.0f : __expf(en2.y));
    #pragma unroll
    for (int d = 1; d < 64; d <<= 1) term += __shfl_xor(term, d);
    const float z = LN2 * svM + __logf(term);

    if (lane == 0) z_ws[w * 64 + b] = z;
}

__global__ void crf_combine_kernel(const float* __restrict__ z_ws,
                                   float* __restrict__ out) {
    const int b = (int)threadIdx.x;
    if (b < B) out[b] = z_ws[B + b] - z_ws[b];
}

extern "C" void kernel_launch(void* const* d_in, const int* in_sizes, int n_in,
                              void* d_out, int out_size, void* d_ws, size_t ws_size,
                              hipStream_t stream) {
    const float* emissions = (const float*)d_in[0];
    const int* mask = (const int*)d_in[1];
    const int* target = (const int*)d_in[2];
    const float* transitions = (const float*)d_in[3];
    const float* start_tr = (const float*)d_in[4];
    const float* end_tr = (const float*)d_in[5];
    const int* forb = (const int*)d_in[6];
    const int* start_forb = (const int*)d_in[7];
    const int* end_forb = (const int*)d_in[8];
    float* out = (float*)d_out;
    float* z_ws = (float*)d_ws;

    crf_chain_kernel<<<dim3(B), dim3(128), 0, stream>>>(
        emissions, mask, target, transitions, start_tr, end_tr,
        forb, start_forb, end_forb, z_ws);
    crf_combine_kernel<<<dim3(1), dim3(64), 0, stream>>>(z_ws, out);
}

// Round 10
// 1111.999 us; speedup vs baseline: 1.4504x; 1.4504x over previous
//
#include <hip/hip_runtime.h>
#include <cstdint>
#include <cstddef>

#define IMPOSSIBLE -10000.0f
#define INV_LN2 1.44269504088896340736f
#define LN2 0.69314718055994530942f

constexpr int B = 64;
constexpr int T = 2048;
constexpr int N = 128;

typedef _Float16 h2 __attribute__((ext_vector_type(2)));
typedef _Float16 h8 __attribute__((ext_vector_type(8)));

typedef __attribute__((address_space(3))) uint32_t lds_u32_t;
typedef __attribute__((address_space(1))) const uint32_t g_u32_t;

__device__ __forceinline__ void gload_lds4(const void* g, void* l) {
    __builtin_amdgcn_global_load_lds((g_u32_t*)g, (lds_u32_t*)l, 4, 0, 0);
}

// One block per chain (c,b), 4 waves / 256 threads (r8 structure).
// j = (wave<<5)|(lane&31); h = lane>>5 selects i-half [64h, 64h+64).
// Exp-domain (validated r8): p'_j = (sum_i p_i E_ij)*exp(em_j)/psum, p in f16,
// psum = sum of the stored array (self-referential normalizer). Mtot += log2.
// NEW: em/target stream through an LDS ring (9 rows; row 8 = dummy) filled by
// wave 0 via global_load_lds 8 steps ahead; constant counted s_waitcnt
// vmcnt(24) per step (6 slots x 4 DMAs in flight) -- no VMEM latency exposure,
// no per-thread global loads in the loop. Raw lgkmcnt+s_barrier once per step.
// fx = exp(em[t+1]) read from ring one step early (off dependent path).
// Bool inputs are int32 per ABI. Pure function of d_in (no atomics/memset).
__global__ __launch_bounds__(256, 1) void crf_chain_kernel(
    const float* __restrict__ emissions,    // [B,T,N]
    const int* __restrict__ mask,           // [B,T]
    const int* __restrict__ target,         // [B,T,N]
    const float* __restrict__ transitions,  // [N,N]
    const float* __restrict__ start_tr,     // [N]
    const float* __restrict__ end_tr,       // [N]
    const int* __restrict__ forb,           // [N,N]
    const int* __restrict__ start_forb,     // [N]
    const int* __restrict__ end_forb,       // [N]
    float* __restrict__ z_ws)               // [128]
{
    const int chain = blockIdx.x;  // 0..127
    const int c = chain >> 6;      // 0 = supervised, 1 = full
    const int b = chain & 63;
    const int tid = (int)threadIdx.x;
    const int wave = tid >> 6;
    const int lane = tid & 63;
    const int h = lane >> 5;
    const int j = (wave << 5) | (lane & 31);
    const bool sup = (c == 0);

    __shared__ __align__(16) _Float16 p_buf[2][128];
    __shared__ __align__(16) float ring_em[9][128];
    __shared__ __align__(16) int ring_tg[9][128];
    __shared__ float wred[4];
    __shared__ int lred[4];

    // ---- sequence length ----
    int lsum = 0;
    for (int k = tid; k < T; k += 256) lsum += (mask[b * T + k] != 0);
    #pragma unroll
    for (int d = 1; d < 64; d <<= 1) lsum += __shfl_xor(lsum, d);
    if (lane == 0) lred[wave] = lsum;
    __syncthreads();
    const int tlast = (lred[0] + lred[1] + lred[2] + lred[3]) - 1;

    // ---- E column slice in f16 pairs, pre-rotated by lane&7 ----
    h2 e2[32];
    #pragma unroll
    for (int k = 0; k < 8; ++k) {
        const int cch = ((lane & 7) + k) & 7;
        const int ib = (h << 6) + (cch << 3);
        #pragma unroll
        for (int m = 0; m < 4; ++m) {
            const int i0 = ib + (m << 1);
            const float f0 = forb[i0 * N + j] ? 0.0f : __expf(transitions[i0 * N + j]);
            const float f1 = forb[(i0 + 1) * N + j] ? 0.0f : __expf(transitions[(i0 + 1) * N + j]);
            e2[(k << 2) + m] = h2{(_Float16)f0, (_Float16)f1};
        }
    }

    const float* embase = emissions + (size_t)b * T * N;
    const int* tgbase = target + (size_t)b * T * N;

    // ---- t = 0 (log2 domain once; normalize so max = 1) ----
    const float st = start_forb[j] ? IMPOSSIBLE : start_tr[j];
    float em0 = embase[j];
    if (sup && !tgbase[j]) em0 = IMPOSSIBLE;
    const float a0l = (em0 + st) * INV_LN2;

    float mx = a0l;
    #pragma unroll
    for (int d = 1; d < 64; d <<= 1) mx = fmaxf(mx, __shfl_xor(mx, d));
    if (lane == 0) wred[wave] = mx;
    __syncthreads();
    mx = fmaxf(fmaxf(wred[0], wred[1]), fmaxf(wred[2], wred[3]));

    float Mtot = rintf(mx);
    const float p0 = exp2f(a0l - Mtot);
    float svE = p0, svM = Mtot;  // covers tlast == 0
    if (h == 0) p_buf[0][j] = (_Float16)p0;

    // ---- prologue DMA: fill ring slots for t = 1..8 (4 DMAs per slot) ----
    if (wave == 0) {
        #pragma unroll
        for (int s = 1; s <= 8; ++s) {
            const int slot = s & 7;
            const float* gse = embase + (size_t)s * N + lane;
            const int* gst = tgbase + (size_t)s * N + lane;
            gload_lds4(gse, &ring_em[slot][0]);
            gload_lds4(gse + 64, &ring_em[slot][64]);
            gload_lds4(gst, &ring_tg[slot][0]);
            gload_lds4(gst + 64, &ring_tg[slot][64]);
        }
        // slots 1,2 guaranteed landed (<=24 outstanding of 32 issued)
        asm volatile("s_waitcnt vmcnt(24)" ::: "memory");
    }
    __syncthreads();

    // fx for t = 1 from ring slot 1
    float em_n = ring_em[1][j];
    int tg_n = sup ? ring_tg[1][j] : 1;
    float fx = (sup && !tg_n) ? 0.0f : __expf(em_n);

    const _Float16* pb0 = &p_buf[0][h << 6];
    const _Float16* pb1 = &p_buf[1][h << 6];
    const h2 one2 = h2{(_Float16)1.0f, (_Float16)1.0f};

    #pragma unroll 2
    for (int t = 1; t < T; ++t) {
        // raw barrier: drain LDS only; DMAs stay in flight
        asm volatile("s_waitcnt lgkmcnt(0)\n\ts_barrier" ::: "memory");

        // issue DMA for step t+8 (dummy row 8 when beyond the sequence)
        if (wave == 0) {
            const int tt = t + 8;
            const int srow = (tt < T) ? tt : 0;
            const int drow = (tt < T) ? (tt & 7) : 8;
            const float* gse = embase + (size_t)srow * N + lane;
            const int* gst = tgbase + (size_t)srow * N + lane;
            gload_lds4(gse, &ring_em[drow][0]);
            gload_lds4(gse + 64, &ring_em[drow][64]);
            gload_lds4(gst, &ring_tg[drow][0]);
            gload_lds4(gst + 64, &ring_tg[drow][64]);
        }

        const int cur = t & 1, prv = cur ^ 1;
        const _Float16* pbase = prv ? pb1 : pb0;

        float acc0 = 0.f, acc1 = 0.f, acc2 = 0.f, acc3 = 0.f;   // matvec
        float ps0 = 0.f, ps1 = 0.f, ps2 = 0.f, ps3 = 0.f;       // p half-sum
        #pragma unroll
        for (int k = 0; k < 8; ++k) {
            const int cch = ((lane & 7) + k) & 7;
            const h8 pv = *reinterpret_cast<const h8*>(pbase + (cch << 3));
            const h2 v0 = __builtin_shufflevector(pv, pv, 0, 1);
            const h2 v1 = __builtin_shufflevector(pv, pv, 2, 3);
            const h2 v2 = __builtin_shufflevector(pv, pv, 4, 5);
            const h2 v3 = __builtin_shufflevector(pv, pv, 6, 7);
            acc0 = __builtin_amdgcn_fdot2(v0, e2[(k << 2) + 0], acc0, false);
            acc1 = __builtin_amdgcn_fdot2(v1, e2[(k << 2) + 1], acc1, false);
            acc2 = __builtin_amdgcn_fdot2(v2, e2[(k << 2) + 2], acc2, false);
            acc3 = __builtin_amdgcn_fdot2(v3, e2[(k << 2) + 3], acc3, false);
            ps0 = __builtin_amdgcn_fdot2(v0, one2, ps0, false);
            ps1 = __builtin_amdgcn_fdot2(v1, one2, ps1, false);
            ps2 = __builtin_amdgcn_fdot2(v2, one2, ps2, false);
            ps3 = __builtin_amdgcn_fdot2(v3, one2, ps3, false);
        }
        const float s = (acc0 + acc1) + (acc2 + acc3);
        const float ph = (ps0 + ps1) + (ps2 + ps3);

        // cross-half sums via permlane32_swap (VALU)
        float x = s, y = s;
        asm volatile("v_permlane32_swap_b32 %0, %1" : "+v"(x), "+v"(y));
        const float stot = x + y;
        float u = ph, v = ph;
        asm volatile("v_permlane32_swap_b32 %0, %1" : "+v"(u), "+v"(v));
        const float psum = fmaxf(u + v, 1e-30f);

        // self-referential rescale (off dependent path)
        const float sc = __builtin_amdgcn_rcpf(psum);
        Mtot += __log2f(psum);

        const float na = stot * (fx * sc);
        if (t == tlast) { svE = na; svM = Mtot; }

        if (h == 0) p_buf[cur][j] = (_Float16)na;

        // fx for t+1 from ring (slot t+1 guaranteed by last step's vmcnt(24))
        {
            const int rrow = (t + 1) & 7;
            em_n = ring_em[rrow][j];
            tg_n = sup ? ring_tg[rrow][j] : 1;
            fx = (sup && !tg_n) ? 0.0f : __expf(em_n);
        }

        // counted wait: ensures slot t+2 landed before next body reads it
        if (wave == 0) {
            asm volatile("s_waitcnt vmcnt(24)" ::: "memory");
        }
    }

    // ---- z = LN2*svM + log( sum_j svE_j * exp(en_j) ); j duplicated x2 ----
    const float en = end_forb[j] ? IMPOSSIBLE : end_tr[j];
    float term = svE * __expf(en);

    #pragma unroll
    for (int d = 1; d < 64; d <<= 1) term += __shfl_xor(term, d);
    __syncthreads();
    if (lane == 0) wred[wave] = term;
    __syncthreads();
    const float tot = (wred[0] + wred[1]) + (wred[2] + wred[3]);  // = 2 * sum
    const float z = LN2 * svM + __logf(tot * 0.5f);

    if (tid == 0) z_ws[chain] = z;
}

__global__ void crf_combine_kernel(const float* __restrict__ z_ws,
                                   float* __restrict__ out) {
    const int b = (int)threadIdx.x;
    if (b < B) out[b] = z_ws[B + b] - z_ws[b];
}

extern "C" void kernel_launch(void* const* d_in, const int* in_sizes, int n_in,
                              void* d_out, int out_size, void* d_ws, size_t ws_size,
                              hipStream_t stream) {
    const float* emissions = (const float*)d_in[0];
    const int* mask = (const int*)d_in[1];
    const int* target = (const int*)d_in[2];
    const float* transitions = (const float*)d_in[3];
    const float* start_tr = (const float*)d_in[4];
    const float* end_tr = (const float*)d_in[5];
    const int* forb = (const int*)d_in[6];
    const int* start_forb = (const int*)d_in[7];
    const int* end_forb = (const int*)d_in[8];
    float* out = (float*)d_out;
    float* z_ws = (float*)d_ws;

    crf_chain_kernel<<<dim3(2 * B), dim3(256), 0, stream>>>(
        emissions, mask, target, transitions, start_tr, end_tr,
        forb, start_forb, end_forb, z_ws);
    crf_combine_kernel<<<dim3(1), dim3(64), 0, stream>>>(z_ws, out);
}

// Round 11
// 892.930 us; speedup vs baseline: 1.8063x; 1.2453x over previous
//
#include <hip/hip_runtime.h>
#include <cstdint>
#include <cstddef>

#define IMPOSSIBLE -10000.0f
#define INV_LN2 1.44269504088896340736f
#define LN2 0.69314718055994530942f

constexpr int B = 64;
constexpr int T = 2048;
constexpr int N = 128;

typedef _Float16 h2 __attribute__((ext_vector_type(2)));
typedef _Float16 h8 __attribute__((ext_vector_type(8)));

typedef __attribute__((address_space(3))) uint32_t lds_u32_t;
typedef __attribute__((address_space(1))) const uint32_t g_u32_t;

__device__ __forceinline__ void gload_lds4(const void* g, void* l) {
    __builtin_amdgcn_global_load_lds((g_u32_t*)g, (lds_u32_t*)l, 4, 0, 0);
}

// r10 structure (4 waves, DMA ring for em/tg, exp-domain + psum normalizer)
// with ONE change: the 8 ds_read_b128 of the p-array are HOISTED into a
// statically-indexed pv[8] array issued back-to-back before any dot2 use.
// Rationale: r9/r10 step-time decomposition shows ~130cy LDS latency exposed
// PER READ when reads and uses interleave (compiler emits per-use lgkmcnt);
// hoisting collapses 8 exposed latencies to 1 (m97-style decreasing waits).
__global__ __launch_bounds__(256, 1) void crf_chain_kernel(
    const float* __restrict__ emissions,    // [B,T,N]
    const int* __restrict__ mask,           // [B,T]
    const int* __restrict__ target,         // [B,T,N]
    const float* __restrict__ transitions,  // [N,N]
    const float* __restrict__ start_tr,     // [N]
    const float* __restrict__ end_tr,       // [N]
    const int* __restrict__ forb,           // [N,N]
    const int* __restrict__ start_forb,     // [N]
    const int* __restrict__ end_forb,       // [N]
    float* __restrict__ z_ws)               // [128]
{
    const int chain = blockIdx.x;  // 0..127
    const int c = chain >> 6;      // 0 = supervised, 1 = full
    const int b = chain & 63;
    const int tid = (int)threadIdx.x;
    const int wave = tid >> 6;
    const int lane = tid & 63;
    const int h = lane >> 5;
    const int j = (wave << 5) | (lane & 31);
    const bool sup = (c == 0);

    __shared__ __align__(16) _Float16 p_buf[2][128];
    __shared__ __align__(16) float ring_em[9][128];
    __shared__ __align__(16) int ring_tg[9][128];
    __shared__ float wred[4];
    __shared__ int lred[4];

    // ---- sequence length ----
    int lsum = 0;
    for (int k = tid; k < T; k += 256) lsum += (mask[b * T + k] != 0);
    #pragma unroll
    for (int d = 1; d < 64; d <<= 1) lsum += __shfl_xor(lsum, d);
    if (lane == 0) lred[wave] = lsum;
    __syncthreads();
    const int tlast = (lred[0] + lred[1] + lred[2] + lred[3]) - 1;

    // ---- E column slice in f16 pairs, pre-rotated by lane&7 ----
    h2 e2[32];
    #pragma unroll
    for (int k = 0; k < 8; ++k) {
        const int cch = ((lane & 7) + k) & 7;
        const int ib = (h << 6) + (cch << 3);
        #pragma unroll
        for (int m = 0; m < 4; ++m) {
            const int i0 = ib + (m << 1);
            const float f0 = forb[i0 * N + j] ? 0.0f : __expf(transitions[i0 * N + j]);
            const float f1 = forb[(i0 + 1) * N + j] ? 0.0f : __expf(transitions[(i0 + 1) * N + j]);
            e2[(k << 2) + m] = h2{(_Float16)f0, (_Float16)f1};
        }
    }

    const float* embase = emissions + (size_t)b * T * N;
    const int* tgbase = target + (size_t)b * T * N;

    // ---- t = 0 (log2 domain once; normalize so max = 1) ----
    const float st = start_forb[j] ? IMPOSSIBLE : start_tr[j];
    float em0 = embase[j];
    if (sup && !tgbase[j]) em0 = IMPOSSIBLE;
    const float a0l = (em0 + st) * INV_LN2;

    float mx = a0l;
    #pragma unroll
    for (int d = 1; d < 64; d <<= 1) mx = fmaxf(mx, __shfl_xor(mx, d));
    if (lane == 0) wred[wave] = mx;
    __syncthreads();
    mx = fmaxf(fmaxf(wred[0], wred[1]), fmaxf(wred[2], wred[3]));

    float Mtot = rintf(mx);
    const float p0 = exp2f(a0l - Mtot);
    float svE = p0, svM = Mtot;  // covers tlast == 0
    if (h == 0) p_buf[0][j] = (_Float16)p0;

    // ---- prologue DMA: fill ring slots for t = 1..8 (4 DMAs per slot) ----
    if (wave == 0) {
        #pragma unroll
        for (int s = 1; s <= 8; ++s) {
            const int slot = s & 7;
            const float* gse = embase + (size_t)s * N + lane;
            const int* gst = tgbase + (size_t)s * N + lane;
            gload_lds4(gse, &ring_em[slot][0]);
            gload_lds4(gse + 64, &ring_em[slot][64]);
            gload_lds4(gst, &ring_tg[slot][0]);
            gload_lds4(gst + 64, &ring_tg[slot][64]);
        }
        asm volatile("s_waitcnt vmcnt(24)" ::: "memory");
    }
    __syncthreads();

    // fx for t = 1 from ring slot 1
    float em_n = ring_em[1][j];
    int tg_n = sup ? ring_tg[1][j] : 1;
    float fx = (sup && !tg_n) ? 0.0f : __expf(em_n);

    const _Float16* pb0 = &p_buf[0][h << 6];
    const _Float16* pb1 = &p_buf[1][h << 6];
    const h2 one2 = h2{(_Float16)1.0f, (_Float16)1.0f};

    #pragma unroll 2
    for (int t = 1; t < T; ++t) {
        // raw barrier: drain LDS only; DMAs stay in flight
        asm volatile("s_waitcnt lgkmcnt(0)\n\ts_barrier" ::: "memory");

        // issue DMA for step t+8 (dummy row 8 when beyond the sequence)
        if (wave == 0) {
            const int tt = t + 8;
            const int srow = (tt < T) ? tt : 0;
            const int drow = (tt < T) ? (tt & 7) : 8;
            const float* gse = embase + (size_t)srow * N + lane;
            const int* gst = tgbase + (size_t)srow * N + lane;
            gload_lds4(gse, &ring_em[drow][0]);
            gload_lds4(gse + 64, &ring_em[drow][64]);
            gload_lds4(gst, &ring_tg[drow][0]);
            gload_lds4(gst + 64, &ring_tg[drow][64]);
        }

        const int cur = t & 1, prv = cur ^ 1;
        const _Float16* pbase = prv ? pb1 : pb0;

        // ---- HOISTED reads: issue all 8 ds_read_b128 before any use ----
        h8 pvv[8];
        #pragma unroll
        for (int k = 0; k < 8; ++k) {
            const int cch = ((lane & 7) + k) & 7;
            pvv[k] = *reinterpret_cast<const h8*>(pbase + (cch << 3));
        }

        float acc0 = 0.f, acc1 = 0.f, acc2 = 0.f, acc3 = 0.f;   // matvec
        float ps0 = 0.f, ps1 = 0.f, ps2 = 0.f, ps3 = 0.f;       // p half-sum
        #pragma unroll
        for (int k = 0; k < 8; ++k) {
            const h8 pv = pvv[k];
            const h2 v0 = __builtin_shufflevector(pv, pv, 0, 1);
            const h2 v1 = __builtin_shufflevector(pv, pv, 2, 3);
            const h2 v2 = __builtin_shufflevector(pv, pv, 4, 5);
            const h2 v3 = __builtin_shufflevector(pv, pv, 6, 7);
            acc0 = __builtin_amdgcn_fdot2(v0, e2[(k << 2) + 0], acc0, false);
            acc1 = __builtin_amdgcn_fdot2(v1, e2[(k << 2) + 1], acc1, false);
            acc2 = __builtin_amdgcn_fdot2(v2, e2[(k << 2) + 2], acc2, false);
            acc3 = __builtin_amdgcn_fdot2(v3, e2[(k << 2) + 3], acc3, false);
            ps0 = __builtin_amdgcn_fdot2(v0, one2, ps0, false);
            ps1 = __builtin_amdgcn_fdot2(v1, one2, ps1, false);
            ps2 = __builtin_amdgcn_fdot2(v2, one2, ps2, false);
            ps3 = __builtin_amdgcn_fdot2(v3, one2, ps3, false);
        }
        const float s = (acc0 + acc1) + (acc2 + acc3);
        const float ph = (ps0 + ps1) + (ps2 + ps3);

        // cross-half sums via permlane32_swap (VALU)
        float x = s, y = s;
        asm volatile("v_permlane32_swap_b32 %0, %1" : "+v"(x), "+v"(y));
        const float stot = x + y;
        float u = ph, v = ph;
        asm volatile("v_permlane32_swap_b32 %0, %1" : "+v"(u), "+v"(v));
        const float psum = fmaxf(u + v, 1e-30f);

        // self-referential rescale (off dependent path)
        const float sc = __builtin_amdgcn_rcpf(psum);
        Mtot += __log2f(psum);

        const float na = stot * (fx * sc);
        if (t == tlast) { svE = na; svM = Mtot; }

        if (h == 0) p_buf[cur][j] = (_Float16)na;

        // fx for t+1 from ring (landing guaranteed by counted vmcnt chain)
        {
            const int rrow = (t + 1) & 7;
            em_n = ring_em[rrow][j];
            tg_n = sup ? ring_tg[rrow][j] : 1;
            fx = (sup && !tg_n) ? 0.0f : __expf(em_n);
        }

        // counted wait: never drains; keeps 6 slots in flight
        if (wave == 0) {
            asm volatile("s_waitcnt vmcnt(24)" ::: "memory");
        }
    }

    // ---- z = LN2*svM + log( sum_j svE_j * exp(en_j) ); j duplicated x2 ----
    const float en = end_forb[j] ? IMPOSSIBLE : end_tr[j];
    float term = svE * __expf(en);

    #pragma unroll
    for (int d = 1; d < 64; d <<= 1) term += __shfl_xor(term, d);
    __syncthreads();
    if (lane == 0) wred[wave] = term;
    __syncthreads();
    const float tot = (wred[0] + wred[1]) + (wred[2] + wred[3]);  // = 2 * sum
    const float z = LN2 * svM + __logf(tot * 0.5f);

    if (tid == 0) z_ws[chain] = z;
}

__global__ void crf_combine_kernel(const float* __restrict__ z_ws,
                                   float* __restrict__ out) {
    const int b = (int)threadIdx.x;
    if (b < B) out[b] = z_ws[B + b] - z_ws[b];
}

extern "C" void kernel_launch(void* const* d_in, const int* in_sizes, int n_in,
                              void* d_out, int out_size, void* d_ws, size_t ws_size,
                              hipStream_t stream) {
    const float* emissions = (const float*)d_in[0];
    const int* mask = (const int*)d_in[1];
    const int* target = (const int*)d_in[2];
    const float* transitions = (const float*)d_in[3];
    const float* start_tr = (const float*)d_in[4];
    const float* end_tr = (const float*)d_in[5];
    const int* forb = (const int*)d_in[6];
    const int* start_forb = (const int*)d_in[7];
    const int* end_forb = (const int*)d_in[8];
    float* out = (float*)d_out;
    float* z_ws = (float*)d_ws;

    crf_chain_kernel<<<dim3(2 * B), dim3(256), 0, stream>>>(
        emissions, mask, target, transitions, start_tr, end_tr,
        forb, start_forb, end_forb, z_ws);
    crf_combine_kernel<<<dim3(1), dim3(64), 0, stream>>>(z_ws, out);
}

// Round 13
// 733.237 us; speedup vs baseline: 2.1997x; 1.2178x over previous
//
#include <hip/hip_runtime.h>
#include <cstdint>
#include <cstddef>

#define IMPOSSIBLE -10000.0f
#define INV_LN2 1.44269504088896340736f
#define LN2 0.69314718055994530942f

constexpr int B = 64;
constexpr int T = 2048;
constexpr int N = 128;
constexpr int WSLOT = 132;  // 128 mid-vector + 1 scale + pad

typedef _Float16 h2 __attribute__((ext_vector_type(2)));
typedef _Float16 h8 __attribute__((ext_vector_type(8)));

typedef __attribute__((address_space(3))) uint32_t lds_u32_t;
typedef __attribute__((address_space(1))) const uint32_t g_u32_t;

__device__ __forceinline__ void gload_lds4(const void* g, void* l) {
    __builtin_amdgcn_global_load_lds((g_u32_t*)g, (lds_u32_t*)l, 4, 0, 0);
}

// Bidirectional split: 256 blocks = (dir, chain). dir 0 = forward from t=0
// (alpha, E-columns), dir 1 = backward from t=tlast (beta, E-rows).
// Both meet at mid = tlast/2; combine kernel computes
// z = LN2*(Ma+Mb) + log(sum_i a_mid[i]*b_mid[i]). Serial depth ~1024.
// Inner loop = r11: 4 waves, f16 p in LDS, hoisted 8x ds_read_b128,
// 96 v_dot2, permlane32_swap, self-referential psum normalizer, em/tg DMA
// ring with counted vmcnt(24), one raw lgkmcnt+s_barrier per step.
// r12 BUG FIX: cur = (it&1)^1 so first iteration reads p_buf[0] (the init
// write); r12's cur=it&1 read uninitialized p_buf[1] -> NaN.
__global__ __launch_bounds__(256, 1) void crf_chain_kernel(
    const float* __restrict__ emissions,    // [B,T,N]
    const int* __restrict__ mask,           // [B,T]
    const int* __restrict__ target,         // [B,T,N]
    const float* __restrict__ transitions,  // [N,N]
    const float* __restrict__ start_tr,     // [N]
    const float* __restrict__ end_tr,       // [N]
    const int* __restrict__ forb,           // [N,N]
    const int* __restrict__ start_forb,     // [N]
    const int* __restrict__ end_forb,       // [N]
    float* __restrict__ ws)                 // [256*WSLOT]
{
    const int dir = (int)blockIdx.x >> 7;   // 0 fwd, 1 bwd
    const int chain = (int)blockIdx.x & 127;
    const int c = chain >> 6;               // 0 = supervised, 1 = full
    const int b = chain & 63;
    const int tid = (int)threadIdx.x;
    const int wave = tid >> 6;
    const int lane = tid & 63;
    const int h = lane >> 5;
    const int j = (wave << 5) | (lane & 31);
    const bool sup = (c == 0);
    const bool fwd = (dir == 0);

    __shared__ __align__(16) _Float16 p_buf[2][128];
    __shared__ __align__(16) float ring_em[9][128];
    __shared__ __align__(16) int ring_tg[9][128];
    __shared__ float wred[4];
    __shared__ int lred[4];

    // ---- sequence length ----
    int lsum = 0;
    for (int k = tid; k < T; k += 256) lsum += (mask[b * T + k] != 0);
    #pragma unroll
    for (int d = 1; d < 64; d <<= 1) lsum += __shfl_xor(lsum, d);
    if (lane == 0) lred[wave] = lsum;
    __syncthreads();
    const int tlast = (lred[0] + lred[1] + lred[2] + lred[3]) - 1;
    const int mid = tlast >> 1;

    // ---- E slice in f16 pairs, pre-rotated by lane&7 ----
    // fwd: e = E[i][j] (column j); bwd: e = E[j][i] (row j)
    h2 e2[32];
    #pragma unroll
    for (int k = 0; k < 8; ++k) {
        const int cch = ((lane & 7) + k) & 7;
        const int ib = (h << 6) + (cch << 3);
        #pragma unroll
        for (int m = 0; m < 4; ++m) {
            const int i0 = ib + (m << 1);
            const int idx0 = fwd ? (i0 * N + j) : (j * N + i0);
            const int idx1 = fwd ? ((i0 + 1) * N + j) : (j * N + i0 + 1);
            const float f0 = forb[idx0] ? 0.0f : __expf(transitions[idx0]);
            const float f1 = forb[idx1] ? 0.0f : __expf(transitions[idx1]);
            e2[(k << 2) + m] = h2{(_Float16)f0, (_Float16)f1};
        }
    }

    const float* embase = emissions + (size_t)b * T * N;
    const int* tgbase = target + (size_t)b * T * N;

    // ---- init at boundary (fwd: t=0 with start_tr; bwd: t=tlast with end_tr) ----
    const float bnd = fwd ? (start_forb[j] ? IMPOSSIBLE : start_tr[j])
                          : (end_forb[j] ? IMPOSSIBLE : end_tr[j]);
    const int r0 = fwd ? 0 : tlast;
    float em0 = embase[(size_t)r0 * N + j];
    int tg0 = sup ? tgbase[(size_t)r0 * N + j] : 1;
    const float v0l = ((tg0 ? em0 : IMPOSSIBLE) + bnd) * INV_LN2;

    float mx = v0l;
    #pragma unroll
    for (int d = 1; d < 64; d <<= 1) mx = fmaxf(mx, __shfl_xor(mx, d));
    if (lane == 0) wred[wave] = mx;
    __syncthreads();
    mx = fmaxf(fmaxf(wred[0], wred[1]), fmaxf(wred[2], wred[3]));

    float Mtot = rintf(mx);
    const float p0 = exp2f(v0l - Mtot);
    if (h == 0) p_buf[0][j] = (_Float16)p0;

    // svE defaults (used when loop doesn't hit t==mid):
    //   fwd (mid==0): a_0 = p0.  bwd (tlast==0): bare enexp, svM=0.
    float svE = fwd ? p0 : __expf(bnd);
    float svM = fwd ? Mtot : 0.0f;

    // ---- prologue DMA: 8 ring rows ahead (fwd: 1..8 ; bwd: tlast-1..tlast-8) ----
    if (wave == 0) {
        #pragma unroll
        for (int s = 1; s <= 8; ++s) {
            const int r = fwd ? s : (tlast - s);
            const int ok = fwd ? 1 : (r >= 0);
            const int srow = ok ? r : 0;
            const int drow = ok ? (r & 7) : 8;
            const float* gse = embase + (size_t)srow * N + lane;
            const int* gst = tgbase + (size_t)srow * N + lane;
            gload_lds4(gse, &ring_em[drow][0]);
            gload_lds4(gse + 64, &ring_em[drow][64]);
            gload_lds4(gst, &ring_tg[drow][0]);
            gload_lds4(gst + 64, &ring_tg[drow][64]);
        }
        asm volatile("s_waitcnt vmcnt(24)" ::: "memory");
    }
    __syncthreads();

    // fx for first iteration (fwd t=1; bwd t=tlast-1); unused if nsteps==0
    float fx;
    {
        const int t1 = fwd ? 1 : (tlast - 1);
        const int rr = t1 & 7;
        const float em_n = ring_em[rr][j];
        const int tg_n = sup ? ring_tg[rr][j] : 1;
        fx = (sup && !tg_n) ? 0.0f : __expf(em_n);
    }

    const _Float16* pb0 = &p_buf[0][h << 6];
    const _Float16* pb1 = &p_buf[1][h << 6];
    const h2 one2 = h2{(_Float16)1.0f, (_Float16)1.0f};

    const int nsteps = fwd ? mid : (tlast - mid);

    #pragma unroll 2
    for (int it = 0; it < nsteps; ++it) {
        const int t = fwd ? (1 + it) : (tlast - 1 - it);

        // raw barrier: drain LDS only; DMAs stay in flight
        asm volatile("s_waitcnt lgkmcnt(0)\n\ts_barrier" ::: "memory");

        // issue DMA for row t+-8 (dummy row 8 when out of range)
        if (wave == 0) {
            const int tt = fwd ? (t + 8) : (t - 8);
            const int ok = fwd ? 1 : (tt >= 0);
            const int srow = ok ? tt : 0;
            const int drow = ok ? (tt & 7) : 8;
            const float* gse = embase + (size_t)srow * N + lane;
            const int* gst = tgbase + (size_t)srow * N + lane;
            gload_lds4(gse, &ring_em[drow][0]);
            gload_lds4(gse + 64, &ring_em[drow][64]);
            gload_lds4(gst, &ring_tg[drow][0]);
            gload_lds4(gst + 64, &ring_tg[drow][64]);
        }

        // parity: first iteration must READ p_buf[0] (init write)
        const int cur = (it & 1) ^ 1, prv = cur ^ 1;
        const _Float16* pbase = prv ? pb1 : pb0;

        // hoisted reads: all 8 ds_read_b128 issued before any use
        h8 pvv[8];
        #pragma unroll
        for (int k = 0; k < 8; ++k) {
            const int cch = ((lane & 7) + k) & 7;
            pvv[k] = *reinterpret_cast<const h8*>(pbase + (cch << 3));
        }

        float acc0 = 0.f, acc1 = 0.f, acc2 = 0.f, acc3 = 0.f;   // matvec
        float ps0 = 0.f, ps1 = 0.f, ps2 = 0.f, ps3 = 0.f;       // p half-sum
        #pragma unroll
        for (int k = 0; k < 8; ++k) {
            const h8 pv = pvv[k];
            const h2 w0 = __builtin_shufflevector(pv, pv, 0, 1);
            const h2 w1 = __builtin_shufflevector(pv, pv, 2, 3);
            const h2 w2 = __builtin_shufflevector(pv, pv, 4, 5);
            const h2 w3 = __builtin_shufflevector(pv, pv, 6, 7);
            acc0 = __builtin_amdgcn_fdot2(w0, e2[(k << 2) + 0], acc0, false);
            acc1 = __builtin_amdgcn_fdot2(w1, e2[(k << 2) + 1], acc1, false);
            acc2 = __builtin_amdgcn_fdot2(w2, e2[(k << 2) + 2], acc2, false);
            acc3 = __builtin_amdgcn_fdot2(w3, e2[(k << 2) + 3], acc3, false);
            ps0 = __builtin_amdgcn_fdot2(w0, one2, ps0, false);
            ps1 = __builtin_amdgcn_fdot2(w1, one2, ps1, false);
            ps2 = __builtin_amdgcn_fdot2(w2, one2, ps2, false);
            ps3 = __builtin_amdgcn_fdot2(w3, one2, ps3, false);
        }
        const float s = (acc0 + acc1) + (acc2 + acc3);
        const float ph = (ps0 + ps1) + (ps2 + ps3);

        // cross-half sums via permlane32_swap (VALU)
        float x = s, y = s;
        asm volatile("v_permlane32_swap_b32 %0, %1" : "+v"(x), "+v"(y));
        const float stot = x + y;
        float u = ph, v = ph;
        asm volatile("v_permlane32_swap_b32 %0, %1" : "+v"(u), "+v"(v));
        const float psum = fmaxf(u + v, 1e-30f);

        // self-referential rescale (off dependent path)
        const float sc = __builtin_amdgcn_rcpf(psum);
        Mtot += __log2f(psum);

        const float na = stot * (fx * sc);
        if (t == mid) {
            // fwd: alpha includes em_mid (post-fx). bwd: beta excludes em_mid.
            svE = fwd ? na : (stot * sc);
            svM = Mtot;
        }

        if (h == 0) p_buf[cur][j] = (_Float16)na;

        // fx for next iteration from ring
        {
            const int nt = fwd ? (t + 1) : (t - 1);
            const int rr = nt & 7;
            const float em_n = ring_em[rr][j];
            const int tg_n = sup ? ring_tg[rr][j] : 1;
            fx = (sup && !tg_n) ? 0.0f : __expf(em_n);
        }

        // counted wait: never drains; keeps 6 slots in flight
        if (wave == 0) {
            asm volatile("s_waitcnt vmcnt(24)" ::: "memory");
        }
    }

    // ---- write mid-vector + scale to workspace ----
    float* wsl = ws + (size_t)(dir * 128 + chain) * WSLOT;
    if (h == 0) wsl[j] = svE;
    if (tid == 0) wsl[128] = svM;
}

// One block per batch b; wave w handles chain c=w (sup/full):
// z_c = LN2*(Ma+Mb) + log(sum_i a_mid[i]*b_mid[i]); out[b] = z_1 - z_0.
__global__ void crf_dot_kernel(const float* __restrict__ ws,
                               float* __restrict__ out) {
    const int b = (int)blockIdx.x;     // 0..63
    const int tid = (int)threadIdx.x;  // 0..127
    const int w = tid >> 6;            // channel
    const int lane = tid & 63;
    const int chain = w * 64 + b;

    const float* fv = ws + (size_t)chain * WSLOT;          // fwd
    const float* bv = ws + (size_t)(128 + chain) * WSLOT;  // bwd

    float term = fv[lane] * bv[lane] + fv[lane + 64] * bv[lane + 64];
    #pragma unroll
    for (int d = 1; d < 64; d <<= 1) term += __shfl_xor(term, d);

    __shared__ float zz[2];
    if (lane == 0) zz[w] = LN2 * (fv[128] + bv[128]) + __logf(term);
    __syncthreads();
    if (tid == 0) out[b] = zz[1] - zz[0];
}

extern "C" void kernel_launch(void* const* d_in, const int* in_sizes, int n_in,
                              void* d_out, int out_size, void* d_ws, size_t ws_size,
                              hipStream_t stream) {
    const float* emissions = (const float*)d_in[0];
    const int* mask = (const int*)d_in[1];
    const int* target = (const int*)d_in[2];
    const float* transitions = (const float*)d_in[3];
    const float* start_tr = (const float*)d_in[4];
    const float* end_tr = (const float*)d_in[5];
    const int* forb = (const int*)d_in[6];
    const int* start_forb = (const int*)d_in[7];
    const int* end_forb = (const int*)d_in[8];
    float* out = (float*)d_out;
    float* ws = (float*)d_ws;

    crf_chain_kernel<<<dim3(4 * B), dim3(256), 0, stream>>>(
        emissions, mask, target, transitions, start_tr, end_tr,
        forb, start_forb, end_forb, ws);
    crf_dot_kernel<<<dim3(B), dim3(128), 0, stream>>>(ws, out);
}

// Round 14
// 656.115 us; speedup vs baseline: 2.4582x; 1.1175x over previous
//
#include <hip/hip_runtime.h>
#include <cstdint>
#include <cstddef>

#define IMPOSSIBLE -10000.0f
#define INV_LN2 1.44269504088896340736f
#define LN2 0.69314718055994530942f

constexpr int B = 64;
constexpr int T = 2048;
constexpr int N = 128;
constexpr int WSLOT = 132;  // 128 mid-vector + 1 scale + pad

typedef _Float16 h2 __attribute__((ext_vector_type(2)));
typedef _Float16 h8 __attribute__((ext_vector_type(8)));

typedef __attribute__((address_space(3))) uint32_t lds_u32_t;
typedef __attribute__((address_space(1))) const uint32_t g_u32_t;

__device__ __forceinline__ void gload_lds4(const void* g, void* l) {
    __builtin_amdgcn_global_load_lds((g_u32_t*)g, (lds_u32_t*)l, 4, 0, 0);
}

struct SmemT {
    __align__(16) _Float16 p_buf[2][128];
    __align__(16) float ring_em[9][128];
    __align__(16) int ring_tg[9][128];
    float wred[4];
};

// Bidirectional split (r13 structure) with COMPILE-TIME direction
// specialization: r13 merged fwd/bwd via runtime ternaries -> compiler
// dropped to 48 VGPR and spilled e2/pvv to scratch (WRITE_SIZE 4->136KB,
// per-step 436->716ns). template<bool FWD> restores r11-grade static
// addressing per direction. Inner loop otherwise identical to r11.
template<bool FWD>
__device__ __forceinline__ void run_chain(
    SmemT& sm,
    const float* __restrict__ embase,
    const int* __restrict__ tgbase,
    const float* __restrict__ transitions,
    const int* __restrict__ forb,
    const float* __restrict__ bnd_tr,   // start_tr (fwd) / end_tr (bwd)
    const int* __restrict__ bnd_forb,   // start_forb / end_forb
    const bool sup, const int tlast,
    float* __restrict__ wsl)
{
    const int tid = (int)threadIdx.x;
    const int wave = tid >> 6;
    const int lane = tid & 63;
    const int h = lane >> 5;
    const int j = (wave << 5) | (lane & 31);
    const int mid = tlast >> 1;

    // ---- E slice in f16 pairs, pre-rotated by lane&7 ----
    // FWD: e = E[i][j] (column j); BWD: e = E[j][i] (row j)
    h2 e2[32];
    #pragma unroll
    for (int k = 0; k < 8; ++k) {
        const int cch = ((lane & 7) + k) & 7;
        const int ib = (h << 6) + (cch << 3);
        #pragma unroll
        for (int m = 0; m < 4; ++m) {
            const int i0 = ib + (m << 1);
            const int idx0 = FWD ? (i0 * N + j) : (j * N + i0);
            const int idx1 = FWD ? ((i0 + 1) * N + j) : (j * N + i0 + 1);
            const float f0 = forb[idx0] ? 0.0f : __expf(transitions[idx0]);
            const float f1 = forb[idx1] ? 0.0f : __expf(transitions[idx1]);
            e2[(k << 2) + m] = h2{(_Float16)f0, (_Float16)f1};
        }
    }

    // ---- init at boundary ----
    const float bnd = bnd_forb[j] ? IMPOSSIBLE : bnd_tr[j];
    const int r0 = FWD ? 0 : tlast;
    const float em0 = embase[(size_t)r0 * N + j];
    const int tg0 = sup ? tgbase[(size_t)r0 * N + j] : 1;
    const float v0l = ((tg0 ? em0 : IMPOSSIBLE) + bnd) * INV_LN2;

    float mx = v0l;
    #pragma unroll
    for (int d = 1; d < 64; d <<= 1) mx = fmaxf(mx, __shfl_xor(mx, d));
    if (lane == 0) sm.wred[wave] = mx;
    __syncthreads();
    mx = fmaxf(fmaxf(sm.wred[0], sm.wred[1]), fmaxf(sm.wred[2], sm.wred[3]));

    float Mtot = rintf(mx);
    const float p0 = exp2f(v0l - Mtot);
    if (h == 0) sm.p_buf[0][j] = (_Float16)p0;

    // defaults when loop never hits t==mid:
    // FWD (mid==0): a_0 = p0.  BWD (tlast==0): bare enexp, svM=0.
    float svE = FWD ? p0 : __expf(bnd);
    float svM = FWD ? Mtot : 0.0f;

    // ---- prologue DMA: 8 ring rows ahead ----
    if (wave == 0) {
        #pragma unroll
        for (int s = 1; s <= 8; ++s) {
            int srow, drow;
            if (FWD) {
                srow = s; drow = s & 7;
            } else {
                const int r = tlast - s;
                const int ok = (r >= 0);
                srow = ok ? r : 0;
                drow = ok ? (r & 7) : 8;
            }
            const float* gse = embase + (size_t)srow * N + lane;
            const int* gst = tgbase + (size_t)srow * N + lane;
            gload_lds4(gse, &sm.ring_em[drow][0]);
            gload_lds4(gse + 64, &sm.ring_em[drow][64]);
            gload_lds4(gst, &sm.ring_tg[drow][0]);
            gload_lds4(gst + 64, &sm.ring_tg[drow][64]);
        }
        asm volatile("s_waitcnt vmcnt(24)" ::: "memory");
    }
    __syncthreads();

    // fx for first iteration (FWD t=1; BWD t=tlast-1); unused if nsteps==0
    float fx;
    {
        const int t1 = FWD ? 1 : (tlast - 1);
        const int rr = t1 & 7;
        const float em_n = sm.ring_em[rr][j];
        const int tg_n = sup ? sm.ring_tg[rr][j] : 1;
        fx = (sup && !tg_n) ? 0.0f : __expf(em_n);
    }

    const _Float16* pb0 = &sm.p_buf[0][h << 6];
    const _Float16* pb1 = &sm.p_buf[1][h << 6];
    const h2 one2 = h2{(_Float16)1.0f, (_Float16)1.0f};

    const int nsteps = FWD ? mid : (tlast - mid);

    #pragma unroll 2
    for (int it = 0; it < nsteps; ++it) {
        const int t = FWD ? (1 + it) : (tlast - 1 - it);

        // raw barrier: drain LDS only; DMAs stay in flight
        asm volatile("s_waitcnt lgkmcnt(0)\n\ts_barrier" ::: "memory");

        // issue DMA for row t+-8 (FWD never OOB: t+8 <= mid+8 < T)
        if (wave == 0) {
            int srow, drow;
            if (FWD) {
                srow = t + 8; drow = srow & 7;
            } else {
                const int tt = t - 8;
                const int ok = (tt >= 0);
                srow = ok ? tt : 0;
                drow = ok ? (tt & 7) : 8;
            }
            const float* gse = embase + (size_t)srow * N + lane;
            const int* gst = tgbase + (size_t)srow * N + lane;
            gload_lds4(gse, &sm.ring_em[drow][0]);
            gload_lds4(gse + 64, &sm.ring_em[drow][64]);
            gload_lds4(gst, &sm.ring_tg[drow][0]);
            gload_lds4(gst + 64, &sm.ring_tg[drow][64]);
        }

        // parity: first iteration reads p_buf[0] (the init write)
        const int cur = (it & 1) ^ 1;
        const _Float16* pbase = (cur ^ 1) ? pb1 : pb0;

        // hoisted reads: all 8 ds_read_b128 issued before any use
        h8 pvv[8];
        #pragma unroll
        for (int k = 0; k < 8; ++k) {
            const int cch = ((lane & 7) + k) & 7;
            pvv[k] = *reinterpret_cast<const h8*>(pbase + (cch << 3));
        }

        float acc0 = 0.f, acc1 = 0.f, acc2 = 0.f, acc3 = 0.f;   // matvec
        float ps0 = 0.f, ps1 = 0.f, ps2 = 0.f, ps3 = 0.f;       // p half-sum
        #pragma unroll
        for (int k = 0; k < 8; ++k) {
            const h8 pv = pvv[k];
            const h2 w0 = __builtin_shufflevector(pv, pv, 0, 1);
            const h2 w1 = __builtin_shufflevector(pv, pv, 2, 3);
            const h2 w2 = __builtin_shufflevector(pv, pv, 4, 5);
            const h2 w3 = __builtin_shufflevector(pv, pv, 6, 7);
            acc0 = __builtin_amdgcn_fdot2(w0, e2[(k << 2) + 0], acc0, false);
            acc1 = __builtin_amdgcn_fdot2(w1, e2[(k << 2) + 1], acc1, false);
            acc2 = __builtin_amdgcn_fdot2(w2, e2[(k << 2) + 2], acc2, false);
            acc3 = __builtin_amdgcn_fdot2(w3, e2[(k << 2) + 3], acc3, false);
            ps0 = __builtin_amdgcn_fdot2(w0, one2, ps0, false);
            ps1 = __builtin_amdgcn_fdot2(w1, one2, ps1, false);
            ps2 = __builtin_amdgcn_fdot2(w2, one2, ps2, false);
            ps3 = __builtin_amdgcn_fdot2(w3, one2, ps3, false);
        }
        const float s = (acc0 + acc1) + (acc2 + acc3);
        const float ph = (ps0 + ps1) + (ps2 + ps3);

        // cross-half sums via permlane32_swap (VALU)
        float x = s, y = s;
        asm volatile("v_permlane32_swap_b32 %0, %1" : "+v"(x), "+v"(y));
        const float stot = x + y;
        float u = ph, v = ph;
        asm volatile("v_permlane32_swap_b32 %0, %1" : "+v"(u), "+v"(v));
        const float psum = fmaxf(u + v, 1e-30f);

        // self-referential rescale (off dependent path)
        const float sc = __builtin_amdgcn_rcpf(psum);
        Mtot += __log2f(psum);

        const float na = stot * (fx * sc);
        if (t == mid) {
            // FWD: alpha includes em_mid (post-fx). BWD: beta excludes em_mid.
            svE = FWD ? na : (stot * sc);
            svM = Mtot;
        }

        if (h == 0) sm.p_buf[cur][j] = (_Float16)na;

        // fx for next iteration from ring
        {
            const int nt = FWD ? (t + 1) : (t - 1);
            const int rr = nt & 7;
            const float em_n = sm.ring_em[rr][j];
            const int tg_n = sup ? sm.ring_tg[rr][j] : 1;
            fx = (sup && !tg_n) ? 0.0f : __expf(em_n);
        }

        // counted wait: never drains; keeps 6 slots in flight
        if (wave == 0) {
            asm volatile("s_waitcnt vmcnt(24)" ::: "memory");
        }
    }

    // ---- write mid-vector + scale to workspace ----
    if (h == 0) wsl[j] = svE;
    if (tid == 0) wsl[128] = svM;
}

__global__ __launch_bounds__(256, 1) void crf_chain_kernel(
    const float* __restrict__ emissions,    // [B,T,N]
    const int* __restrict__ mask,           // [B,T]
    const int* __restrict__ target,         // [B,T,N]
    const float* __restrict__ transitions,  // [N,N]
    const float* __restrict__ start_tr,     // [N]
    const float* __restrict__ end_tr,       // [N]
    const int* __restrict__ forb,           // [N,N]
    const int* __restrict__ start_forb,     // [N]
    const int* __restrict__ end_forb,       // [N]
    float* __restrict__ ws)                 // [256*WSLOT]
{
    __shared__ SmemT sm;
    __shared__ int lred[4];

    const int dir = (int)blockIdx.x >> 7;   // 0 fwd, 1 bwd
    const int chain = (int)blockIdx.x & 127;
    const int c = chain >> 6;               // 0 = supervised, 1 = full
    const int b = chain & 63;
    const int tid = (int)threadIdx.x;
    const int wave = tid >> 6;
    const int lane = tid & 63;
    const bool sup = (c == 0);

    // ---- sequence length (common) ----
    int lsum = 0;
    for (int k = tid; k < T; k += 256) lsum += (mask[b * T + k] != 0);
    #pragma unroll
    for (int d = 1; d < 64; d <<= 1) lsum += __shfl_xor(lsum, d);
    if (lane == 0) lred[wave] = lsum;
    __syncthreads();
    const int tlast = (lred[0] + lred[1] + lred[2] + lred[3]) - 1;

    const float* embase = emissions + (size_t)b * T * N;
    const int* tgbase = target + (size_t)b * T * N;
    float* wsl = ws + (size_t)(dir * 128 + chain) * WSLOT;

    if (dir == 0) {
        run_chain<true>(sm, embase, tgbase, transitions, forb,
                        start_tr, start_forb, sup, tlast, wsl);
    } else {
        run_chain<false>(sm, embase, tgbase, transitions, forb,
                         end_tr, end_forb, sup, tlast, wsl);
    }
}

// One block per batch b; wave w handles chain c=w (sup/full):
// z_c = LN2*(Ma+Mb) + log(sum_i a_mid[i]*b_mid[i]); out[b] = z_1 - z_0.
__global__ void crf_dot_kernel(const float* __restrict__ ws,
                               float* __restrict__ out) {
    const int b = (int)blockIdx.x;     // 0..63
    const int tid = (int)threadIdx.x;  // 0..127
    const int w = tid >> 6;            // channel
    const int lane = tid & 63;
    const int chain = w * 64 + b;

    const float* fv = ws + (size_t)chain * WSLOT;          // fwd
    const float* bv = ws + (size_t)(128 + chain) * WSLOT;  // bwd

    float term = fv[lane] * bv[lane] + fv[lane + 64] * bv[lane + 64];
    #pragma unroll
    for (int d = 1; d < 64; d <<= 1) term += __shfl_xor(term, d);

    __shared__ float zz[2];
    if (lane == 0) zz[w] = LN2 * (fv[128] + bv[128]) + __logf(term);
    __syncthreads();
    if (tid == 0) out[b] = zz[1] - zz[0];
}

extern "C" void kernel_launch(void* const* d_in, const int* in_sizes, int n_in,
                              void* d_out, int out_size, void* d_ws, size_t ws_size,
                              hipStream_t stream) {
    const float* emissions = (const float*)d_in[0];
    const int* mask = (const int*)d_in[1];
    const int* target = (const int*)d_in[2];
    const float* transitions = (const float*)d_in[3];
    const float* start_tr = (const float*)d_in[4];
    const float* end_tr = (const float*)d_in[5];
    const int* forb = (const int*)d_in[6];
    const int* start_forb = (const int*)d_in[7];
    const int* end_forb = (const int*)d_in[8];
    float* out = (float*)d_out;
    float* ws = (float*)d_ws;

    crf_chain_kernel<<<dim3(4 * B), dim3(256), 0, stream>>>(
        emissions, mask, target, transitions, start_tr, end_tr,
        forb, start_forb, end_forb, ws);
    crf_dot_kernel<<<dim3(B), dim3(128), 0, stream>>>(ws, out);
}

// Round 15
// 453.923 us; speedup vs baseline: 3.5532x; 1.4454x over previous
//
#include <hip/hip_runtime.h>
#include <cstdint>
#include <cstddef>

#define IMPOSSIBLE -10000.0f
#define INV_LN2 1.44269504088896340736f
#define LN2 0.69314718055994530942f

constexpr int B = 64;
constexpr int T = 2048;
constexpr int N = 128;
constexpr int WSLOT = 132;  // 128 mid-vector + 1 scale + pad

typedef _Float16 h2 __attribute__((ext_vector_type(2)));
typedef _Float16 h8 __attribute__((ext_vector_type(8)));

typedef __attribute__((address_space(3))) uint32_t lds_u32_t;
typedef __attribute__((address_space(1))) const uint32_t g_u32_t;

__device__ __forceinline__ void gload_lds4(const void* g, void* l) {
    __builtin_amdgcn_global_load_lds((g_u32_t*)g, (lds_u32_t*)l, 4, 0, 0);
}

struct SmemT {
    __align__(16) _Float16 p_buf[2][128];
    __align__(16) float ring_em[9][128];
    __align__(16) int ring_tg[9][128];
    float wred[4];
};

// Bidirectional CRF with FULL compile-time specialization:
//  FWD  : direction (alpha from t=0 / beta from t=tlast)
//  SUP  : supervised channel (needs target ring; 4 DMAs/slot + vmcnt(24))
//         vs full channel (2 DMAs/slot + vmcnt(12), no tg reads)
//  FM   : full-mask fast path -> tlast=T-1, mid, nsteps all LITERALS
//         (r14 ran ~640ns/step vs r11's 436 with the only structural delta
//          being runtime trip count; this is the A/B against that theory).
// Inner loop: f16 p in LDS, hoisted 8x ds_read_b128, 96 (or 96) v_dot2,
// permlane32_swap cross-half sums, self-referential psum normalizer,
// em(/tg) DMA ring with counted vmcnt, one raw lgkmcnt+s_barrier per step.
template<bool FWD, bool SUP, bool FM>
__device__ __forceinline__ void run_chain(
    SmemT& sm,
    const float* __restrict__ embase,
    const int* __restrict__ tgbase,
    const float* __restrict__ transitions,
    const int* __restrict__ forb,
    const float* __restrict__ bnd_tr,   // start_tr (fwd) / end_tr (bwd)
    const int* __restrict__ bnd_forb,   // start_forb / end_forb
    const int tlast_rt,
    float* __restrict__ wsl)
{
    const int tid = (int)threadIdx.x;
    const int wave = tid >> 6;
    const int lane = tid & 63;
    const int h = lane >> 5;
    const int j = (wave << 5) | (lane & 31);

    const int tlast = FM ? (T - 1) : tlast_rt;
    const int mid = tlast >> 1;
    const int nsteps = FWD ? mid : (tlast - mid);

    // ---- E slice in f16 pairs, pre-rotated by lane&7 ----
    // FWD: e = E[i][j] (column j); BWD: e = E[j][i] (row j)
    h2 e2[32];
    #pragma unroll
    for (int k = 0; k < 8; ++k) {
        const int cch = ((lane & 7) + k) & 7;
        const int ib = (h << 6) + (cch << 3);
        #pragma unroll
        for (int m = 0; m < 4; ++m) {
            const int i0 = ib + (m << 1);
            const int idx0 = FWD ? (i0 * N + j) : (j * N + i0);
            const int idx1 = FWD ? ((i0 + 1) * N + j) : (j * N + i0 + 1);
            const float f0 = forb[idx0] ? 0.0f : __expf(transitions[idx0]);
            const float f1 = forb[idx1] ? 0.0f : __expf(transitions[idx1]);
            e2[(k << 2) + m] = h2{(_Float16)f0, (_Float16)f1};
        }
    }

    // ---- init at boundary ----
    const float bnd = bnd_forb[j] ? IMPOSSIBLE : bnd_tr[j];
    const int r0 = FWD ? 0 : tlast;
    const float em0 = embase[(size_t)r0 * N + j];
    const int tg0 = SUP ? tgbase[(size_t)r0 * N + j] : 1;
    const float v0l = ((tg0 ? em0 : IMPOSSIBLE) + bnd) * INV_LN2;

    float mx = v0l;
    #pragma unroll
    for (int d = 1; d < 64; d <<= 1) mx = fmaxf(mx, __shfl_xor(mx, d));
    if (lane == 0) sm.wred[wave] = mx;
    __syncthreads();
    mx = fmaxf(fmaxf(sm.wred[0], sm.wred[1]), fmaxf(sm.wred[2], sm.wred[3]));

    float Mtot = rintf(mx);
    const float p0 = exp2f(v0l - Mtot);
    if (h == 0) sm.p_buf[0][j] = (_Float16)p0;

    // defaults when loop never hits t==mid (FWD mid==0 / BWD tlast==0)
    float svE = FWD ? p0 : __expf(bnd);
    float svM = FWD ? Mtot : 0.0f;

    // ---- prologue DMA: 8 ring rows ahead ----
    if (wave == 0) {
        #pragma unroll
        for (int s = 1; s <= 8; ++s) {
            int srow, drow;
            if (FWD) {
                srow = s; drow = s & 7;
            } else {
                const int r = tlast - s;
                const int ok = FM ? 1 : (r >= 0);   // FM: tlast-8 >= 2039
                srow = ok ? r : 0;
                drow = ok ? (r & 7) : 8;
            }
            const float* gse = embase + (size_t)srow * N + lane;
            gload_lds4(gse, &sm.ring_em[drow][0]);
            gload_lds4(gse + 64, &sm.ring_em[drow][64]);
            if (SUP) {
                const int* gst = tgbase + (size_t)srow * N + lane;
                gload_lds4(gst, &sm.ring_tg[drow][0]);
                gload_lds4(gst + 64, &sm.ring_tg[drow][64]);
            }
        }
        if (SUP) asm volatile("s_waitcnt vmcnt(24)" ::: "memory");
        else     asm volatile("s_waitcnt vmcnt(12)" ::: "memory");
    }
    __syncthreads();

    // fx for first iteration (FWD t=1; BWD t=tlast-1); unused if nsteps==0
    float fx;
    {
        const int t1 = FWD ? 1 : (tlast - 1);
        const int rr = t1 & 7;
        const float em_n = sm.ring_em[rr][j];
        if (SUP) {
            const int tg_n = sm.ring_tg[rr][j];
            fx = tg_n ? __expf(em_n) : 0.0f;
        } else {
            fx = __expf(em_n);
        }
    }

    const _Float16* pb0 = &sm.p_buf[0][h << 6];
    const _Float16* pb1 = &sm.p_buf[1][h << 6];
    const h2 one2 = h2{(_Float16)1.0f, (_Float16)1.0f};

    #pragma unroll 2
    for (int it = 0; it < nsteps; ++it) {
        const int t = FWD ? (1 + it) : (tlast - 1 - it);

        // raw barrier: drain LDS only; DMAs stay in flight
        asm volatile("s_waitcnt lgkmcnt(0)\n\ts_barrier" ::: "memory");

        // issue DMA for row t+-8 (FWD never OOB: t+8 <= mid+8 < T)
        if (wave == 0) {
            int srow, drow;
            if (FWD) {
                srow = t + 8; drow = srow & 7;
            } else {
                const int tt = t - 8;
                const int ok = (tt >= 0);
                srow = ok ? tt : 0;
                drow = ok ? (tt & 7) : 8;
            }
            const float* gse = embase + (size_t)srow * N + lane;
            gload_lds4(gse, &sm.ring_em[drow][0]);
            gload_lds4(gse + 64, &sm.ring_em[drow][64]);
            if (SUP) {
                const int* gst = tgbase + (size_t)srow * N + lane;
                gload_lds4(gst, &sm.ring_tg[drow][0]);
                gload_lds4(gst + 64, &sm.ring_tg[drow][64]);
            }
        }

        // parity: first iteration reads p_buf[0] (the init write)
        const int cur = (it & 1) ^ 1;
        const _Float16* pbase = (cur ^ 1) ? pb1 : pb0;

        // hoisted reads: all 8 ds_read_b128 issued before any use
        h8 pvv[8];
        #pragma unroll
        for (int k = 0; k < 8; ++k) {
            const int cch = ((lane & 7) + k) & 7;
            pvv[k] = *reinterpret_cast<const h8*>(pbase + (cch << 3));
        }

        float acc0 = 0.f, acc1 = 0.f, acc2 = 0.f, acc3 = 0.f;   // matvec
        float ps0 = 0.f, ps1 = 0.f, ps2 = 0.f, ps3 = 0.f;       // p half-sum
        #pragma unroll
        for (int k = 0; k < 8; ++k) {
            const h8 pv = pvv[k];
            const h2 w0 = __builtin_shufflevector(pv, pv, 0, 1);
            const h2 w1 = __builtin_shufflevector(pv, pv, 2, 3);
            const h2 w2 = __builtin_shufflevector(pv, pv, 4, 5);
            const h2 w3 = __builtin_shufflevector(pv, pv, 6, 7);
            acc0 = __builtin_amdgcn_fdot2(w0, e2[(k << 2) + 0], acc0, false);
            acc1 = __builtin_amdgcn_fdot2(w1, e2[(k << 2) + 1], acc1, false);
            acc2 = __builtin_amdgcn_fdot2(w2, e2[(k << 2) + 2], acc2, false);
            acc3 = __builtin_amdgcn_fdot2(w3, e2[(k << 2) + 3], acc3, false);
            ps0 = __builtin_amdgcn_fdot2(w0, one2, ps0, false);
            ps1 = __builtin_amdgcn_fdot2(w1, one2, ps1, false);
            ps2 = __builtin_amdgcn_fdot2(w2, one2, ps2, false);
            ps3 = __builtin_amdgcn_fdot2(w3, one2, ps3, false);
        }
        const float s = (acc0 + acc1) + (acc2 + acc3);
        const float ph = (ps0 + ps1) + (ps2 + ps3);

        // cross-half sums via permlane32_swap (VALU)
        float x = s, y = s;
        asm volatile("v_permlane32_swap_b32 %0, %1" : "+v"(x), "+v"(y));
        const float stot = x + y;
        float u = ph, v = ph;
        asm volatile("v_permlane32_swap_b32 %0, %1" : "+v"(u), "+v"(v));
        const float psum = fmaxf(u + v, 1e-30f);

        // self-referential rescale (off dependent path)
        const float sc = __builtin_amdgcn_rcpf(psum);
        Mtot += __log2f(psum);

        const float na = stot * (fx * sc);
        if (t == mid) {
            // FWD: alpha includes em_mid (post-fx). BWD: beta excludes em_mid.
            svE = FWD ? na : (stot * sc);
            svM = Mtot;
        }

        if (h == 0) sm.p_buf[cur][j] = (_Float16)na;

        // fx for next iteration from ring
        {
            const int nt = FWD ? (t + 1) : (t - 1);
            const int rr = nt & 7;
            const float em_n = sm.ring_em[rr][j];
            if (SUP) {
                const int tg_n = sm.ring_tg[rr][j];
                fx = tg_n ? __expf(em_n) : 0.0f;
            } else {
                fx = __expf(em_n);
            }
        }

        // counted wait: never drains; keeps 6 slots in flight
        if (wave == 0) {
            if (SUP) asm volatile("s_waitcnt vmcnt(24)" ::: "memory");
            else     asm volatile("s_waitcnt vmcnt(12)" ::: "memory");
        }
    }

    // ---- write mid-vector + scale to workspace ----
    if (h == 0) wsl[j] = svE;
    if (tid == 0) wsl[128] = svM;
}

__global__ __launch_bounds__(256, 1) void crf_chain_kernel(
    const float* __restrict__ emissions,    // [B,T,N]
    const int* __restrict__ mask,           // [B,T]
    const int* __restrict__ target,         // [B,T,N]
    const float* __restrict__ transitions,  // [N,N]
    const float* __restrict__ start_tr,     // [N]
    const float* __restrict__ end_tr,       // [N]
    const int* __restrict__ forb,           // [N,N]
    const int* __restrict__ start_forb,     // [N]
    const int* __restrict__ end_forb,       // [N]
    float* __restrict__ ws)                 // [256*WSLOT]
{
    __shared__ SmemT sm;
    __shared__ int lred[4];

    const int dir = (int)blockIdx.x >> 7;   // 0 fwd, 1 bwd
    const int chain = (int)blockIdx.x & 127;
    const int c = chain >> 6;               // 0 = supervised, 1 = full
    const int b = chain & 63;
    const int tid = (int)threadIdx.x;
    const int wave = tid >> 6;
    const int lane = tid & 63;

    // ---- sequence length (common) ----
    int lsum = 0;
    for (int k = tid; k < T; k += 256) lsum += (mask[b * T + k] != 0);
    #pragma unroll
    for (int d = 1; d < 64; d <<= 1) lsum += __shfl_xor(lsum, d);
    if (lane == 0) lred[wave] = lsum;
    __syncthreads();
    const int tlast = (lred[0] + lred[1] + lred[2] + lred[3]) - 1;
    const bool fm = (tlast == T - 1);

    const float* embase = emissions + (size_t)b * T * N;
    const int* tgbase = target + (size_t)b * T * N;
    float* wsl = ws + (size_t)(dir * 128 + chain) * WSLOT;

    if (dir == 0) {
        if (c == 0) {
            if (fm) run_chain<true, true, true>(sm, embase, tgbase, transitions, forb, start_tr, start_forb, tlast, wsl);
            else    run_chain<true, true, false>(sm, embase, tgbase, transitions, forb, start_tr, start_forb, tlast, wsl);
        } else {
            if (fm) run_chain<true, false, true>(sm, embase, tgbase, transitions, forb, start_tr, start_forb, tlast, wsl);
            else    run_chain<true, false, false>(sm, embase, tgbase, transitions, forb, start_tr, start_forb, tlast, wsl);
        }
    } else {
        if (c == 0) {
            if (fm) run_chain<false, true, true>(sm, embase, tgbase, transitions, forb, end_tr, end_forb, tlast, wsl);
            else    run_chain<false, true, false>(sm, embase, tgbase, transitions, forb, end_tr, end_forb, tlast, wsl);
        } else {
            if (fm) run_chain<false, false, true>(sm, embase, tgbase, transitions, forb, end_tr, end_forb, tlast, wsl);
            else    run_chain<false, false, false>(sm, embase, tgbase, transitions, forb, end_tr, end_forb, tlast, wsl);
        }
    }
}

// One block per batch b; wave w handles chain c=w (sup/full):
// z_c = LN2*(Ma+Mb) + log(sum_i a_mid[i]*b_mid[i]); out[b] = z_1 - z_0.
__global__ void crf_dot_kernel(const float* __restrict__ ws,
                               float* __restrict__ out) {
    const int b = (int)blockIdx.x;     // 0..63
    const int tid = (int)threadIdx.x;  // 0..127
    const int w = tid >> 6;            // channel
    const int lane = tid & 63;
    const int chain = w * 64 + b;

    const float* fv = ws + (size_t)chain * WSLOT;          // fwd
    const float* bv = ws + (size_t)(128 + chain) * WSLOT;  // bwd

    float term = fv[lane] * bv[lane] + fv[lane + 64] * bv[lane + 64];
    #pragma unroll
    for (int d = 1; d < 64; d <<= 1) term += __shfl_xor(term, d);

    __shared__ float zz[2];
    if (lane == 0) zz[w] = LN2 * (fv[128] + bv[128]) + __logf(term);
    __syncthreads();
    if (tid == 0) out[b] = zz[1] - zz[0];
}

extern "C" void kernel_launch(void* const* d_in, const int* in_sizes, int n_in,
                              void* d_out, int out_size, void* d_ws, size_t ws_size,
                              hipStream_t stream) {
    const float* emissions = (const float*)d_in[0];
    const int* mask = (const int*)d_in[1];
    const int* target = (const int*)d_in[2];
    const float* transitions = (const float*)d_in[3];
    const float* start_tr = (const float*)d_in[4];
    const float* end_tr = (const float*)d_in[5];
    const int* forb = (const int*)d_in[6];
    const int* start_forb = (const int*)d_in[7];
    const int* end_forb = (const int*)d_in[8];
    float* out = (float*)d_out;
    float* ws = (float*)d_ws;

    crf_chain_kernel<<<dim3(4 * B), dim3(256), 0, stream>>>(
        emissions, mask, target, transitions, start_tr, end_tr,
        forb, start_forb, end_forb, ws);
    crf_dot_kernel<<<dim3(B), dim3(128), 0, stream>>>(ws, out);
}